// Round 5
// baseline (199.727 us; speedup 1.0000x reference)
//
#include <hip/hip_runtime.h>
#include <hip/hip_fp16.h>
#include <math.h>

#define N 512
#define NPAD(i) ((i) + ((i) >> 5))
#define FSZ 532
#define NCOL 257           // Hermitian: columns v = 0..256 only
// mask: (u-256)^2 + (v-256)^2 <= 51.2^2 (integer dist^2 exact in fp32)
#define RAD2 2621.44f
#define SQ2H 0.70710678f
#define K2_BLOCKS (65 * 32)

// ---------------------------------------------------------------------------
// In-register 8-point DFT, natural order in/out.
// ---------------------------------------------------------------------------
__device__ __forceinline__ void dft8(float (&xr)[8], float (&xi)[8]) {
    float e0r = xr[0] + xr[4], e0i = xi[0] + xi[4];
    float e1r = xr[0] - xr[4], e1i = xi[0] - xi[4];
    float e2r = xr[2] + xr[6], e2i = xi[2] + xi[6];
    float e3r = xr[2] - xr[6], e3i = xi[2] - xi[6];
    float E0r = e0r + e2r, E0i = e0i + e2i;
    float E2r = e0r - e2r, E2i = e0i - e2i;
    float E1r = e1r + e3i, E1i = e1i - e3r;
    float E3r = e1r - e3i, E3i = e1i + e3r;
    float o0r = xr[1] + xr[5], o0i = xi[1] + xi[5];
    float o1r = xr[1] - xr[5], o1i = xi[1] - xi[5];
    float o2r = xr[3] + xr[7], o2i = xi[3] + xi[7];
    float o3r = xr[3] - xr[7], o3i = xi[3] - xi[7];
    float O0r = o0r + o2r, O0i = o0i + o2i;
    float O2r = o0r - o2r, O2i = o0i - o2i;
    float O1r = o1r + o3i, O1i = o1i - o3r;
    float O3r = o1r - o3i, O3i = o1i + o3r;
    float t1r = SQ2H * (O1r + O1i), t1i = SQ2H * (O1i - O1r);
    float t2r = O2i,                t2i = -O2r;
    float t3r = SQ2H * (O3i - O3r), t3i = -SQ2H * (O3r + O3i);
    xr[0] = E0r + O0r; xi[0] = E0i + O0i;
    xr[4] = E0r - O0r; xi[4] = E0i - O0i;
    xr[1] = E1r + t1r; xi[1] = E1i + t1i;
    xr[5] = E1r - t1r; xi[5] = E1i - t1i;
    xr[2] = E2r + t2r; xi[2] = E2i + t2i;
    xr[6] = E2r - t2r; xi[6] = E2i - t2i;
    xr[3] = E3r + t3r; xi[3] = E3i + t3i;
    xr[7] = E3r - t3r; xi[7] = E3i - t3i;
}

// ---------------------------------------------------------------------------
// Wave-level 512-pt FFT. Lane l, reg k holds x[8*l + k] on input.
// Out: lane l, reg t holds X[br6(l) + 64*t].
// ---------------------------------------------------------------------------
__device__ __forceinline__ void fft512_regs(float (&zr)[8], float (&zi)[8],
                                            int l) {
#pragma unroll
    for (int half = 32; half >= 1; half >>= 1) {
        const int j = l & (half - 1);
        const float f = (float)j * (0.5f / (float)half);   // revolutions
        const float c = __builtin_amdgcn_cosf(f);
        const float s = __builtin_amdgcn_sinf(f);
        const bool up = (l & half) != 0;
        const float sgn = up ? -1.0f : 1.0f;
        const float wc  = up ? c : 1.0f;
        const float ws  = up ? s : 0.0f;
#pragma unroll
        for (int k = 0; k < 8; ++k) {
            float pr = __shfl_xor(zr[k], half);
            float pi = __shfl_xor(zi[k], half);
            float tr = fmaf(sgn, zr[k], pr);
            float ti = fmaf(sgn, zi[k], pi);
            zr[k] = tr * wc + ti * ws;
            zi[k] = ti * wc - tr * ws;
        }
    }
    const int w = __brev((unsigned)l) >> 26;
#pragma unroll
    for (int k = 1; k < 8; ++k) {
        const float f = (float)(k * w) * (1.0f / 512.0f);
        const float c = __builtin_amdgcn_cosf(f);
        const float s = __builtin_amdgcn_sinf(f);
        float tr = zr[k] * c + zi[k] * s;
        float ti = zi[k] * c - zr[k] * s;
        zr[k] = tr; zi[k] = ti;
    }
    dft8(zr, zi);
}

// ---------------------------------------------------------------------------
// K1: grayscale + packed row-pair FFT + Hermitian unpack + transposed fp16
// write. 512 thr = 8 waves = 16 rows. Output bufh[b][v][h] as half2(re,im).
// ---------------------------------------------------------------------------
__global__ __launch_bounds__(512) void k_gray_rowfft(
    const float* __restrict__ img, __half2* __restrict__ bufh) {
    __shared__ float sr[8][FSZ], si[8][FSZ];
    const int t = threadIdx.x, wv = t >> 6, l = t & 63;
    const int b = blockIdx.y, tile = blockIdx.x;
    const size_t plane = (size_t)N * N;
    const float* base = img + (size_t)b * 3 * plane;
    const int he = tile * 16 + 2 * wv;
    const float* p0 = base + (size_t)he * N;
    const float* p1 = p0 + N;

    const float4* c0e = (const float4*)(p0);
    const float4* c1e = (const float4*)(p0 + plane);
    const float4* c2e = (const float4*)(p0 + 2 * plane);
    const float4* c0o = (const float4*)(p1);
    const float4* c1o = (const float4*)(p1 + plane);
    const float4* c2o = (const float4*)(p1 + 2 * plane);

    float zr[8], zi[8];
    const float inv3 = 1.0f / 3.0f;
#pragma unroll
    for (int q = 0; q < 2; ++q) {
        int idx = 2 * l + q;
        float4 a = c0e[idx], bb = c1e[idx], c = c2e[idx];
        float4 d = c0o[idx], e = c1o[idx], g = c2o[idx];
        zr[4 * q + 0] = (a.x + bb.x + c.x) * inv3;
        zr[4 * q + 1] = (a.y + bb.y + c.y) * inv3;
        zr[4 * q + 2] = (a.z + bb.z + c.z) * inv3;
        zr[4 * q + 3] = (a.w + bb.w + c.w) * inv3;
        zi[4 * q + 0] = (d.x + e.x + g.x) * inv3;
        zi[4 * q + 1] = (d.y + e.y + g.y) * inv3;
        zi[4 * q + 2] = (d.z + e.z + g.z) * inv3;
        zi[4 * q + 3] = (d.w + e.w + g.w) * inv3;
    }

    fft512_regs(zr, zi, l);

    const int w = __brev((unsigned)l) >> 26;
#pragma unroll
    for (int k = 0; k < 8; ++k) {
        int u = w + 64 * k;
        sr[wv][NPAD(u)] = zr[k];
        si[wv][NPAD(u)] = zi[k];
    }
    __syncthreads();

    // unpack F_even/F_odd; lane emits both parities of pair p = t&7 as one
    // 8-byte store (two half2 complexes = columns h2, h2+1) per v-slice.
    const int p = t & 7;
    const int h2 = 2 * p;
    const int slot = t >> 3;                   // 0..63
    __half2* ob = bufh + (size_t)b * NCOL * N;
#pragma unroll
    for (int it = 0; it < 5; ++it) {
        int v = slot + 64 * it;
        if (v < NCOL) {
            int vn = (N - v) & (N - 1);
            float Zr  = sr[p][NPAD(v)],  Zi  = si[p][NPAD(v)];
            float Zr2 = sr[p][NPAD(vn)], Zi2 = si[p][NPAD(vn)];
            __half2 fe = __floats2half2_rn(0.5f * (Zr + Zr2),
                                           0.5f * (Zi - Zi2));
            __half2 fo = __floats2half2_rn(0.5f * (Zi + Zi2),
                                           0.5f * (Zr2 - Zr));
            __half2 pairv[2] = {fe, fo};
            *(uint2*)(&ob[(size_t)v * N + tile * 16 + h2]) =
                *(const uint2*)pairv;
        }
    }
}

// ---------------------------------------------------------------------------
// K2: column FFT in registers + masked/total reduction + (last block) final
// ratio-mean. 256 thr = 4 waves = 4 columns; 16B loads (4 fp16 complex each).
// ---------------------------------------------------------------------------
__global__ __launch_bounds__(256) void k_colfft_reduce(
    const __half2* __restrict__ bufh, float* __restrict__ acc,
    unsigned* __restrict__ cnt, float* __restrict__ out) {
    __shared__ float red[8];
    __shared__ int isLast;
    const int t = threadIdx.x, wv = t >> 6, l = t & 63;
    const int b = blockIdx.y;
    const int v = blockIdx.x * 4 + wv;         // 0..259 (257.. dummies)
    const int vv = v > 256 ? 256 : v;

    const uint4* col = (const uint4*)(bufh + ((size_t)b * NCOL + vv) * N);
    float zr[8], zi[8];
#pragma unroll
    for (int q = 0; q < 2; ++q) {
        uint4 raw = col[2 * l + q];            // 4 complex: 8l+4q .. 8l+4q+3
        float2 z0 = __half22float2(*(const __half2*)&raw.x);
        float2 z1 = __half22float2(*(const __half2*)&raw.y);
        float2 z2 = __half22float2(*(const __half2*)&raw.z);
        float2 z3 = __half22float2(*(const __half2*)&raw.w);
        zr[4 * q + 0] = z0.x; zi[4 * q + 0] = z0.y;
        zr[4 * q + 1] = z1.x; zi[4 * q + 1] = z1.y;
        zr[4 * q + 2] = z2.x; zi[4 * q + 2] = z2.y;
        zr[4 * q + 3] = z3.x; zi[4 * q + 3] = z3.y;
    }

    fft512_regs(zr, zi, l);

    const float wcol = (v == 0 || v == 256) ? 1.0f : (v < 256 ? 2.0f : 0.0f);
    const float dx = (float)(vv - 256);
    const float dx2 = dx * dx;
    const int w = __brev((unsigned)l) >> 26;
    float msum = 0.0f, tsum = 0.0f;
#pragma unroll
    for (int k = 0; k < 8; ++k) {
        int u = w + 64 * k;
        float mag = sqrtf(zr[k] * zr[k] + zi[k] * zi[k]);
        tsum += mag;
        float dy = (float)(u - 256);
        if (dy * dy + dx2 <= RAD2) msum += mag;
    }
    msum *= wcol; tsum *= wcol;
#pragma unroll
    for (int off = 32; off > 0; off >>= 1) {
        msum += __shfl_down(msum, off);
        tsum += __shfl_down(tsum, off);
    }
    if (l == 0) { red[wv * 2] = msum; red[wv * 2 + 1] = tsum; }
    __syncthreads();
    if (t == 0) {
        atomicAdd(&acc[b * 2 + 0], red[0] + red[2] + red[4] + red[6]);
        atomicAdd(&acc[b * 2 + 1], red[1] + red[3] + red[5] + red[7]);
        __threadfence();
        unsigned tick = atomicAdd(cnt, 1u);
        isLast = (tick == (unsigned)(K2_BLOCKS - 1));
    }
    __syncthreads();
    if (isLast) {
        // coherent read of device-scope accumulators via atomic RMW of 0
        float r = 0.0f;
        if (t < 32) {
            float m = atomicAdd(&acc[t * 2 + 0], 0.0f);
            float s = atomicAdd(&acc[t * 2 + 1], 0.0f);
            r = m / s;
        }
        if (t < 64) {
#pragma unroll
            for (int off = 32; off > 0; off >>= 1) r += __shfl_down(r, off);
            if (t == 0) out[0] = r * (1.0f / 32.0f);
        }
    }
}

extern "C" void kernel_launch(void* const* d_in, const int* in_sizes, int n_in,
                              void* d_out, int out_size, void* d_ws,
                              size_t ws_size, hipStream_t stream) {
    const float* img = (const float*)d_in[0];
    float* out = (float*)d_out;

    __half2* bufh = (__half2*)d_ws;            // [32][257][512] half2 ~ 16.8MB
    const size_t buf_bytes = (size_t)32 * NCOL * N * sizeof(__half2);
    float* acc = (float*)((char*)d_ws + buf_bytes);   // 64 floats
    unsigned* cnt = (unsigned*)(acc + 64);            // 1 counter

    hipMemsetAsync(acc, 0, 65 * sizeof(float), stream);

    dim3 g1(N / 16, 32);                       // 32 row-tiles x 32 images
    k_gray_rowfft<<<g1, 512, 0, stream>>>(img, bufh);

    dim3 g2((NCOL + 3) / 4, 32);               // 65 col-groups x 32 images
    k_colfft_reduce<<<g2, 256, 0, stream>>>(bufh, acc, cnt, out);
}

// Round 6
// 175.894 us; speedup vs baseline: 1.1355x; 1.1355x over previous
//
#include <hip/hip_runtime.h>
#include <math.h>

#define N 512
#define NPAD(i) ((i) + ((i) >> 5))
#define FSZ 532
#define NCOL 257           // Hermitian: columns v = 0..256 only
// mask: (u-256)^2 + (v-256)^2 <= 51.2^2 (integer dist^2 exact in fp32)
#define RAD2 2621.44f
#define SQ2H 0.70710678f

// ---------------------------------------------------------------------------
// In-register 8-point DFT, natural order in/out.
// ---------------------------------------------------------------------------
__device__ __forceinline__ void dft8(float (&xr)[8], float (&xi)[8]) {
    float e0r = xr[0] + xr[4], e0i = xi[0] + xi[4];
    float e1r = xr[0] - xr[4], e1i = xi[0] - xi[4];
    float e2r = xr[2] + xr[6], e2i = xi[2] + xi[6];
    float e3r = xr[2] - xr[6], e3i = xi[2] - xi[6];
    float E0r = e0r + e2r, E0i = e0i + e2i;
    float E2r = e0r - e2r, E2i = e0i - e2i;
    float E1r = e1r + e3i, E1i = e1i - e3r;
    float E3r = e1r - e3i, E3i = e1i + e3r;
    float o0r = xr[1] + xr[5], o0i = xi[1] + xi[5];
    float o1r = xr[1] - xr[5], o1i = xi[1] - xi[5];
    float o2r = xr[3] + xr[7], o2i = xi[3] + xi[7];
    float o3r = xr[3] - xr[7], o3i = xi[3] - xi[7];
    float O0r = o0r + o2r, O0i = o0i + o2i;
    float O2r = o0r - o2r, O2i = o0i - o2i;
    float O1r = o1r + o3i, O1i = o1i - o3r;
    float O3r = o1r - o3i, O3i = o1i + o3r;
    float t1r = SQ2H * (O1r + O1i), t1i = SQ2H * (O1i - O1r);
    float t2r = O2i,                t2i = -O2r;
    float t3r = SQ2H * (O3i - O3r), t3i = -SQ2H * (O3r + O3i);
    xr[0] = E0r + O0r; xi[0] = E0i + O0i;
    xr[4] = E0r - O0r; xi[4] = E0i - O0i;
    xr[1] = E1r + t1r; xi[1] = E1i + t1i;
    xr[5] = E1r - t1r; xi[5] = E1i - t1i;
    xr[2] = E2r + t2r; xi[2] = E2i + t2i;
    xr[6] = E2r - t2r; xi[6] = E2i - t2i;
    xr[3] = E3r + t3r; xi[3] = E3i + t3i;
    xr[7] = E3r - t3r; xi[7] = E3i - t3i;
}

// ---------------------------------------------------------------------------
// TWO interleaved wave-level 512-pt FFTs (shared twiddles, overlapped
// latency). Lane l, reg k holds x[8*l + k] on input.
// Out: lane l, reg t holds X[br6(l) + 64*t].
// ---------------------------------------------------------------------------
__device__ __forceinline__ void fft512_x2(float (&ar)[8], float (&ai)[8],
                                          float (&br)[8], float (&bi)[8],
                                          int l) {
#pragma unroll
    for (int half = 32; half >= 1; half >>= 1) {
        const int j = l & (half - 1);
        const float f = (float)j * (0.5f / (float)half);   // revolutions
        const float c = __builtin_amdgcn_cosf(f);
        const float s = __builtin_amdgcn_sinf(f);
        const bool up = (l & half) != 0;
        const float sgn = up ? -1.0f : 1.0f;
        const float wc  = up ? c : 1.0f;
        const float ws  = up ? s : 0.0f;
#pragma unroll
        for (int k = 0; k < 8; ++k) {
            float pr = __shfl_xor(ar[k], half);
            float pi = __shfl_xor(ai[k], half);
            float qr = __shfl_xor(br[k], half);
            float qi = __shfl_xor(bi[k], half);
            float tr = fmaf(sgn, ar[k], pr);
            float ti = fmaf(sgn, ai[k], pi);
            float ur = fmaf(sgn, br[k], qr);
            float ui = fmaf(sgn, bi[k], qi);
            ar[k] = tr * wc + ti * ws;
            ai[k] = ti * wc - tr * ws;
            br[k] = ur * wc + ui * ws;
            bi[k] = ui * wc - ur * ws;
        }
    }
    const int w = __brev((unsigned)l) >> 26;
#pragma unroll
    for (int k = 1; k < 8; ++k) {
        const float f = (float)(k * w) * (1.0f / 512.0f);
        const float c = __builtin_amdgcn_cosf(f);
        const float s = __builtin_amdgcn_sinf(f);
        float tr = ar[k] * c + ai[k] * s;
        float ti = ai[k] * c - ar[k] * s;
        ar[k] = tr; ai[k] = ti;
        float ur = br[k] * c + bi[k] * s;
        float ui = bi[k] * c - br[k] * s;
        br[k] = ur; bi[k] = ui;
    }
    dft8(ar, ai);
    dft8(br, bi);
}

// ---------------------------------------------------------------------------
// K1: grayscale + 2 packed row-pair FFTs per wave + Hermitian unpack +
// transposed write. 512 thr = 8 waves = 32 rows. Output buf[b][v][h].
// ---------------------------------------------------------------------------
__global__ __launch_bounds__(512) void k_gray_rowfft(
    const float* __restrict__ img, float2* __restrict__ buf) {
    __shared__ float sr[16][FSZ], si[16][FSZ];
    const int t = threadIdx.x, wv = t >> 6, l = t & 63;
    const int b = blockIdx.y, tile = blockIdx.x;   // rows tile*32..tile*32+31
    const size_t plane = (size_t)N * N;
    const float* base = img + (size_t)b * 3 * plane;
    const int r0 = tile * 32 + 4 * wv;             // this wave: rows r0..r0+3

    const float inv3 = 1.0f / 3.0f;
    auto loadgray = [&](const float* p, float (&g)[8]) {
        const float4* c0 = (const float4*)p;
        const float4* c1 = (const float4*)(p + plane);
        const float4* c2 = (const float4*)(p + 2 * plane);
#pragma unroll
        for (int q = 0; q < 2; ++q) {
            float4 a = c0[2 * l + q], bb = c1[2 * l + q], c = c2[2 * l + q];
            g[4 * q + 0] = (a.x + bb.x + c.x) * inv3;
            g[4 * q + 1] = (a.y + bb.y + c.y) * inv3;
            g[4 * q + 2] = (a.z + bb.z + c.z) * inv3;
            g[4 * q + 3] = (a.w + bb.w + c.w) * inv3;
        }
    };

    float arr[8], ari[8], brr[8], bri[8];
    loadgray(base + (size_t)(r0 + 0) * N, arr);    // FFT A: rows r0, r0+1
    loadgray(base + (size_t)(r0 + 1) * N, ari);
    loadgray(base + (size_t)(r0 + 2) * N, brr);    // FFT B: rows r0+2, r0+3
    loadgray(base + (size_t)(r0 + 3) * N, bri);

    fft512_x2(arr, ari, brr, bri, l);

    // park packed spectra at natural index v = br6(l) + 64*k
    const int w = __brev((unsigned)l) >> 26;
    const int sA = 2 * wv, sB = 2 * wv + 1;        // pair-slab indices
#pragma unroll
    for (int k = 0; k < 8; ++k) {
        int u = w + 64 * k;
        sr[sA][NPAD(u)] = arr[k]; si[sA][NPAD(u)] = ari[k];
        sr[sB][NPAD(u)] = brr[k]; si[sB][NPAD(u)] = bri[k];
    }
    __syncthreads();

    // unpack F_even/F_odd; lane emits both parities of pair p = t&15 as one
    // float4 (columns h2, h2+1 of the 32-row tile) per v-slice.
    const int p = t & 15;
    const int h2 = 2 * p;
    const int slot = t >> 4;                       // 0..31
    float2* ob = buf + (size_t)b * NCOL * N;
#pragma unroll
    for (int it = 0; it < 9; ++it) {
        int v = slot + 32 * it;
        if (v < NCOL) {
            int vn = (N - v) & (N - 1);
            float Zr  = sr[p][NPAD(v)],  Zi  = si[p][NPAD(v)];
            float Zr2 = sr[p][NPAD(vn)], Zi2 = si[p][NPAD(vn)];
            float4 o;
            o.x = 0.5f * (Zr + Zr2);               // F_even.re
            o.y = 0.5f * (Zi - Zi2);               // F_even.im
            o.z = 0.5f * (Zi + Zi2);               // F_odd.re
            o.w = 0.5f * (Zr2 - Zr);               // F_odd.im
            *(float4*)(&ob[(size_t)v * N + tile * 32 + h2]) = o;
        }
    }
}

// ---------------------------------------------------------------------------
// K2: 2 column FFTs per wave (registers only) + masked/total reduction with
// Hermitian weights. 256 thr = 4 waves = 8 columns.
// ---------------------------------------------------------------------------
__global__ __launch_bounds__(256) void k_colfft_reduce(
    const float2* __restrict__ buf, float* __restrict__ acc) {
    __shared__ float red[8];
    const int t = threadIdx.x, wv = t >> 6, l = t & 63;
    const int b = blockIdx.y;
    const int v0 = blockIdx.x * 8 + 2 * wv;        // columns v0, v0+1
    const int v1 = v0 + 1;
    const int c0 = v0 > 256 ? 256 : v0;
    const int c1 = v1 > 256 ? 256 : v1;

    const float4* colA = (const float4*)(buf + ((size_t)b * NCOL + c0) * N);
    const float4* colB = (const float4*)(buf + ((size_t)b * NCOL + c1) * N);
    float arr[8], ari[8], brr[8], bri[8];
#pragma unroll
    for (int q = 0; q < 4; ++q) {
        float4 zA = colA[4 * l + q];               // complex 8l+2q, 8l+2q+1
        float4 zB = colB[4 * l + q];
        arr[2 * q] = zA.x; ari[2 * q] = zA.y;
        arr[2 * q + 1] = zA.z; ari[2 * q + 1] = zA.w;
        brr[2 * q] = zB.x; bri[2 * q] = zB.y;
        brr[2 * q + 1] = zB.z; bri[2 * q + 1] = zB.w;
    }

    fft512_x2(arr, ari, brr, bri, l);

    const float wA = (v0 == 0 || v0 == 256) ? 1.0f : (v0 < 256 ? 2.0f : 0.0f);
    const float wB = (v1 == 0 || v1 == 256) ? 1.0f : (v1 < 256 ? 2.0f : 0.0f);
    const float dxA = (float)(c0 - 256), dxA2 = dxA * dxA;
    const float dxB = (float)(c1 - 256), dxB2 = dxB * dxB;
    const int w = __brev((unsigned)l) >> 26;
    float msum = 0.0f, tsum = 0.0f;
#pragma unroll
    for (int k = 0; k < 8; ++k) {
        int u = w + 64 * k;
        float dy = (float)(u - 256);
        float dy2 = dy * dy;
        float magA = sqrtf(arr[k] * arr[k] + ari[k] * ari[k]) * wA;
        float magB = sqrtf(brr[k] * brr[k] + bri[k] * bri[k]) * wB;
        tsum += magA + magB;
        float m = 0.0f;
        if (dy2 + dxA2 <= RAD2) m += magA;
        if (dy2 + dxB2 <= RAD2) m += magB;
        msum += m;
    }
#pragma unroll
    for (int off = 32; off > 0; off >>= 1) {
        msum += __shfl_down(msum, off);
        tsum += __shfl_down(tsum, off);
    }
    if (l == 0) { red[wv * 2] = msum; red[wv * 2 + 1] = tsum; }
    __syncthreads();
    if (t == 0) {
        atomicAdd(&acc[b * 2 + 0], red[0] + red[2] + red[4] + red[6]);
        atomicAdd(&acc[b * 2 + 1], red[1] + red[3] + red[5] + red[7]);
    }
}

// K3: mean over batch of ratios.
__global__ void k_final(const float* __restrict__ acc,
                        float* __restrict__ out) {
    int t = threadIdx.x;                           // 64 threads
    float r = 0.0f;
    if (t < 32) r = acc[t * 2 + 0] / acc[t * 2 + 1];
#pragma unroll
    for (int off = 32; off > 0; off >>= 1) r += __shfl_down(r, off);
    if (t == 0) out[0] = r * (1.0f / 32.0f);
}

extern "C" void kernel_launch(void* const* d_in, const int* in_sizes, int n_in,
                              void* d_out, int out_size, void* d_ws,
                              size_t ws_size, hipStream_t stream) {
    const float* img = (const float*)d_in[0];
    float* out = (float*)d_out;

    float2* buf = (float2*)d_ws;                   // [32][257][512] ~ 33.7MB
    const size_t buf_bytes = (size_t)32 * NCOL * N * sizeof(float2);
    float* acc = (float*)((char*)d_ws + buf_bytes);

    hipMemsetAsync(acc, 0, 64 * sizeof(float), stream);

    dim3 g1(N / 32, 32);                           // 16 row-tiles x 32 images
    k_gray_rowfft<<<g1, 512, 0, stream>>>(img, buf);

    dim3 g2((NCOL + 7) / 8, 32);                   // 33 col-groups x 32 images
    k_colfft_reduce<<<g2, 256, 0, stream>>>(buf, acc);

    k_final<<<1, 64, 0, stream>>>(acc, out);
}